// Round 1
// baseline (368.094 us; speedup 1.0000x reference)
//
#include <hip/hip_runtime.h>

// Problem constants (fixed by the reference: shape (20,1,128,128,128) fp32)
#define NBATCH 20
#define ELEMS_PER_BATCH (128 * 128 * 128)       // 2,097,152
#define BLOCKS_PER_BATCH 128
#define THREADS 256
#define V4_PER_THREAD 16                        // 128 blk * 256 thr * 16 * 4 = 2,097,152
#define NPART (NBATCH * BLOCKS_PER_BATCH)       // 2560 partials

// Kernel 1: per-block partial reductions.
//   bce  : sum of y*clamp(log x,-100) + (1-y)*clamp(log1p(-x),-100)
//   pred : count of (x <= 0.5)   [reference: xb = x>0.5 ? 1:0 ; counts xb==0]
//   true : count of ((int)y == 0) == (y < 1.0) for y >= 0
__global__ __launch_bounds__(THREADS) void partial_kernel(
    const float* __restrict__ x, const float* __restrict__ y,
    float* __restrict__ bce_part, int* __restrict__ pred_part,
    int* __restrict__ true_part) {
  const int b   = blockIdx.y;
  const int seg = blockIdx.x;
  const int tid = threadIdx.x;

  const long base4 = (long)b * (ELEMS_PER_BATCH / 4) +
                     (long)seg * (THREADS * V4_PER_THREAD);
  const float4* __restrict__ x4 = (const float4*)x;
  const float4* __restrict__ y4 = (const float4*)y;

  float bce = 0.0f;
  int pc = 0, tc = 0;

#pragma unroll
  for (int k = 0; k < V4_PER_THREAD; ++k) {
    const long idx = base4 + (long)k * THREADS + tid;
    const float4 xv = x4[idx];
    const float4 yv = y4[idx];

    {
      const float xx = xv.x, yy = yv.x;
      float lx  = fmaxf(logf(xx),    -100.0f);
      float l1  = fmaxf(log1pf(-xx), -100.0f);
      bce += yy * lx + (1.0f - yy) * l1;
      pc += (xx <= 0.5f);
      tc += (yy < 1.0f);
    }
    {
      const float xx = xv.y, yy = yv.y;
      float lx  = fmaxf(logf(xx),    -100.0f);
      float l1  = fmaxf(log1pf(-xx), -100.0f);
      bce += yy * lx + (1.0f - yy) * l1;
      pc += (xx <= 0.5f);
      tc += (yy < 1.0f);
    }
    {
      const float xx = xv.z, yy = yv.z;
      float lx  = fmaxf(logf(xx),    -100.0f);
      float l1  = fmaxf(log1pf(-xx), -100.0f);
      bce += yy * lx + (1.0f - yy) * l1;
      pc += (xx <= 0.5f);
      tc += (yy < 1.0f);
    }
    {
      const float xx = xv.w, yy = yv.w;
      float lx  = fmaxf(logf(xx),    -100.0f);
      float l1  = fmaxf(log1pf(-xx), -100.0f);
      bce += yy * lx + (1.0f - yy) * l1;
      pc += (xx <= 0.5f);
      tc += (yy < 1.0f);
    }
  }

  __shared__ float sb[THREADS];
  __shared__ int   sp[THREADS];
  __shared__ int   st[THREADS];
  sb[tid] = bce; sp[tid] = pc; st[tid] = tc;
  __syncthreads();
#pragma unroll
  for (int s = THREADS / 2; s > 0; s >>= 1) {
    if (tid < s) {
      sb[tid] += sb[tid + s];
      sp[tid] += sp[tid + s];
      st[tid] += st[tid + s];
    }
    __syncthreads();
  }
  if (tid == 0) {
    const int o = b * BLOCKS_PER_BATCH + seg;
    bce_part[o]  = sb[0];
    pred_part[o] = sp[0];
    true_part[o] = st[0];
  }
}

// Kernel 2: single block. Double-precision BCE total; per-batch POR; compose.
__global__ __launch_bounds__(THREADS) void final_kernel(
    const float* __restrict__ bce_part, const int* __restrict__ pred_part,
    const int* __restrict__ true_part, float* __restrict__ out) {
  const int tid = threadIdx.x;
  __shared__ double sred[THREADS];
  __shared__ float  spor[NBATCH];

  double local = 0.0;
  for (int i = tid; i < NPART; i += THREADS) local += (double)bce_part[i];
  sred[tid] = local;
  __syncthreads();
#pragma unroll
  for (int s = THREADS / 2; s > 0; s >>= 1) {
    if (tid < s) sred[tid] += sred[tid + s];
    __syncthreads();
  }

  if (tid < NBATCH) {
    int pc = 0, tc = 0;
    for (int k = 0; k < BLOCKS_PER_BATCH; ++k) {
      pc += pred_part[tid * BLOCKS_PER_BATCH + k];
      tc += true_part[tid * BLOCKS_PER_BATCH + k];
    }
    const float pp = (float)pc / (float)ELEMS_PER_BATCH;
    const float pt = (float)tc / (float)ELEMS_PER_BATCH;
    const float d = pp - pt;
    spor[tid] = d * d;
  }
  __syncthreads();

  if (tid == 0) {
    float pore_sum = 0.0f;
#pragma unroll
    for (int b = 0; b < NBATCH; ++b) pore_sum += spor[b];
    const float pore = pore_sum / (float)NBATCH;
    const double total = (double)NBATCH * (double)ELEMS_PER_BATCH;
    const float mse = (float)(-(sred[0] / total));
    out[0] = pore + mse;
    out[1] = pore;
  }
}

extern "C" void kernel_launch(void* const* d_in, const int* in_sizes, int n_in,
                              void* d_out, int out_size, void* d_ws, size_t ws_size,
                              hipStream_t stream) {
  const float* x = (const float*)d_in[0];
  const float* y = (const float*)d_in[1];
  float* out = (float*)d_out;

  // Workspace layout: [NPART floats][NPART ints][NPART ints] — every slot is
  // fully overwritten by partial_kernel, so no init needed despite 0xAA poison.
  float* bce_part  = (float*)d_ws;
  int*   pred_part = (int*)(bce_part + NPART);
  int*   true_part = pred_part + NPART;

  dim3 grid(BLOCKS_PER_BATCH, NBATCH);
  partial_kernel<<<grid, THREADS, 0, stream>>>(x, y, bce_part, pred_part, true_part);
  final_kernel<<<1, THREADS, 0, stream>>>(bce_part, pred_part, true_part, out);
}

// Round 2
// 338.413 us; speedup vs baseline: 1.0877x; 1.0877x over previous
//
#include <hip/hip_runtime.h>

// Problem constants (fixed by the reference: shape (20,1,128,128,128) fp32)
#define NBATCH 20
#define ELEMS_PER_BATCH (128 * 128 * 128)       // 2,097,152
#define BLOCKS_PER_BATCH 128
#define THREADS 256
#define V4_PER_THREAD 16                        // 128 blk * 256 thr * 16 * 4 = 2,097,152
#define NPART (NBATCH * BLOCKS_PER_BATCH)       // 2560 partials

#define LN2 0.69314718055994530942
// torch clamps log at -100 -> in log2 space: -100/ln2
#define LOG2_CLAMP (-144.26950408889634f)

// Kernel 1: per-block partial reductions.
// BCE accumulated in log2 space via hardware v_log_f32 (quarter-rate trans
// pipe) instead of OCML logf/log1pf software expansions — Round-1 counters
// showed VALUBusy ~100% / HBM 14%: the libm logs were the bottleneck.
//   log1p(-x) -> log2(1-x): exact for x>=0.5 (Sterbenz), ~1e-7 rel otherwise.
__global__ __launch_bounds__(THREADS) void partial_kernel(
    const float* __restrict__ x, const float* __restrict__ y,
    float* __restrict__ bce_part, int* __restrict__ pred_part,
    int* __restrict__ true_part) {
  const int b   = blockIdx.y;
  const int seg = blockIdx.x;
  const int tid = threadIdx.x;

  const long base4 = (long)b * (ELEMS_PER_BATCH / 4) +
                     (long)seg * (THREADS * V4_PER_THREAD);
  const float4* __restrict__ x4 = (const float4*)x;
  const float4* __restrict__ y4 = (const float4*)y;

  float bce2 = 0.0f;  // sum in log2 units
  int pc = 0, tc = 0;

#pragma unroll
  for (int k = 0; k < V4_PER_THREAD; ++k) {
    const long idx = base4 + (long)k * THREADS + tid;
    const float4 xv = x4[idx];
    const float4 yv = y4[idx];

#pragma unroll
    for (int c = 0; c < 4; ++c) {
      const float xx = (c == 0) ? xv.x : (c == 1) ? xv.y : (c == 2) ? xv.z : xv.w;
      const float yy = (c == 0) ? yv.x : (c == 1) ? yv.y : (c == 2) ? yv.z : yv.w;
      const float lx = fmaxf(__builtin_amdgcn_logf(xx),        LOG2_CLAMP);
      const float l1 = fmaxf(__builtin_amdgcn_logf(1.0f - xx), LOG2_CLAMP);
      // y*lx + (1-y)*l1 = l1 + y*(lx - l1)
      bce2 += l1 + yy * (lx - l1);
      pc += (xx <= 0.5f);
      tc += (yy < 1.0f);
    }
  }

  __shared__ float sb[THREADS];
  __shared__ int   sp[THREADS];
  __shared__ int   st[THREADS];
  sb[tid] = bce2; sp[tid] = pc; st[tid] = tc;
  __syncthreads();
#pragma unroll
  for (int s = THREADS / 2; s > 0; s >>= 1) {
    if (tid < s) {
      sb[tid] += sb[tid + s];
      sp[tid] += sp[tid + s];
      st[tid] += st[tid + s];
    }
    __syncthreads();
  }
  if (tid == 0) {
    const int o = b * BLOCKS_PER_BATCH + seg;
    bce_part[o]  = (float)(sb[0] * LN2);  // back to natural-log units
    pred_part[o] = sp[0];
    true_part[o] = st[0];
  }
}

// Kernel 2: single block. Double-precision BCE total; per-batch POR; compose.
__global__ __launch_bounds__(THREADS) void final_kernel(
    const float* __restrict__ bce_part, const int* __restrict__ pred_part,
    const int* __restrict__ true_part, float* __restrict__ out) {
  const int tid = threadIdx.x;
  __shared__ double sred[THREADS];
  __shared__ float  spor[NBATCH];

  double local = 0.0;
  for (int i = tid; i < NPART; i += THREADS) local += (double)bce_part[i];
  sred[tid] = local;
  __syncthreads();
#pragma unroll
  for (int s = THREADS / 2; s > 0; s >>= 1) {
    if (tid < s) sred[tid] += sred[tid + s];
    __syncthreads();
  }

  if (tid < NBATCH) {
    int pc = 0, tc = 0;
    for (int k = 0; k < BLOCKS_PER_BATCH; ++k) {
      pc += pred_part[tid * BLOCKS_PER_BATCH + k];
      tc += true_part[tid * BLOCKS_PER_BATCH + k];
    }
    const float pp = (float)pc / (float)ELEMS_PER_BATCH;
    const float pt = (float)tc / (float)ELEMS_PER_BATCH;
    const float d = pp - pt;
    spor[tid] = d * d;
  }
  __syncthreads();

  if (tid == 0) {
    float pore_sum = 0.0f;
#pragma unroll
    for (int b = 0; b < NBATCH; ++b) pore_sum += spor[b];
    const float pore = pore_sum / (float)NBATCH;
    const double total = (double)NBATCH * (double)ELEMS_PER_BATCH;
    const float mse = (float)(-(sred[0] / total));
    out[0] = pore + mse;
    out[1] = pore;
  }
}

extern "C" void kernel_launch(void* const* d_in, const int* in_sizes, int n_in,
                              void* d_out, int out_size, void* d_ws, size_t ws_size,
                              hipStream_t stream) {
  const float* x = (const float*)d_in[0];
  const float* y = (const float*)d_in[1];
  float* out = (float*)d_out;

  // Workspace layout: [NPART floats][NPART ints][NPART ints] — every slot is
  // fully overwritten by partial_kernel, so no init needed despite 0xAA poison.
  float* bce_part  = (float*)d_ws;
  int*   pred_part = (int*)(bce_part + NPART);
  int*   true_part = pred_part + NPART;

  dim3 grid(BLOCKS_PER_BATCH, NBATCH);
  partial_kernel<<<grid, THREADS, 0, stream>>>(x, y, bce_part, pred_part, true_part);
  final_kernel<<<1, THREADS, 0, stream>>>(bce_part, pred_part, true_part, out);
}